// Round 1
// baseline (224.155 us; speedup 1.0000x reference)
//
#include <hip/hip_runtime.h>

// ROIAlign (FPN multi-level, crop_and_resize style) for MI355X.
// Shapes (fixed): B=2, N=512, C=256, OUT=7, IMG=1024,
// strides {4,8,16,32} -> fm H=W {256,128,64,32}.
// Output read back by harness as float32 (reference f16 -> "else float*").
//
// R6 structure: block = 448 threads = 7 waves = one FULL ROI (7x7 cells).
// Wave ix owns output column ix; the 7 rows are a fully-unrolled loop.
//  - per-ROI setup (log2/sqrt/level dispatch) computed once, not 7x
//  - x-side bilinear params + column base pointers are loop-invariant
//  - unrolled row loop lets the scheduler hoist next-row corner loads
//    over current-row lerps (register pipelining)
//  - 1024 blocks = 4 blocks/CU exactly; __launch_bounds__(448,7) keeps
//    28 waves/CU resident (VGPR cap ~72) so the whole grid is co-resident
//  - all 49 cells of a ROI on ONE CU -> L1/L2 locality by construction
//    (replaces the R5 XCD swizzle)

#define B_SZ   2
#define N_ROI  512
#define CCH    256
#define OUT_S  7
#define NCELL  (OUT_S * OUT_S)

typedef float nfloat4 __attribute__((ext_vector_type(4)));

__global__ __launch_bounds__(448, 7)
void roialign_kernel(const float* __restrict__ fm2,
                     const float* __restrict__ fm3,
                     const float* __restrict__ fm4,
                     const float* __restrict__ fm5,
                     const float* __restrict__ rois,
                     float* __restrict__ out)
{
    const int bn = blockIdx.x;            // ROI id 0..1023
    const int ix = threadIdx.x >> 6;      // column 0..6 (wave id in block)
    const int b  = bn >> 9;               // batch (N=512)

    // ---- per-ROI setup (computed once per thread, wave-uniform) ----
    const float4 roi = ((const float4*)rois)[bn];   // x1,y1,x2,y2
    const float x1 = roi.x, y1 = roi.y;
    const float w  = roi.z - roi.x;
    const float h  = roi.w - roi.y;

    float lvf = log2f(sqrtf(w * h) * (1.0f / 224.0f)) + 4.0f;
    int lv = (int)rintf(lvf);                   // RNE, matches jnp.round
    lv = min(max(lv, 2), 5) - 2;                // 0..3

    const float* fm = (lv == 0) ? fm2 : (lv == 1) ? fm3 : (lv == 2) ? fm4 : fm5;
    const int    H      = 256 >> lv;            // H == W
    const float  stride = (float)(4 << lv);
    const float  scale  = (float)(H - 1) / (stride * (float)H);

    // ---- x-side params: loop-invariant for this column wave ----
    const float gx = (float)ix * (1.0f / 6.0f);
    const float cx = (x1 + gx * w) * scale;     // ref: ((x1+g*w)/stride/W)*(W-1)
    const int   vx = (cx >= 0.0f) & (cx <= (float)(H - 1));
    const float cxc = fminf(fmaxf(cx, 0.0f), (float)(H - 1));
    const int   x0  = (int)floorf(cxc);
    const float xl  = cxc - (float)x0;
    const int   x1i = min(x0 + 1, H - 1);

    const int c = (threadIdx.x & 63) * 4;       // 4 channels per lane

    const float*  base = fm + (size_t)b * (size_t)H * (size_t)H * CCH;
    const float*  col0 = base + (size_t)x0  * CCH + c;   // left  column, +y*rowStride
    const float*  col1 = base + (size_t)x1i * CCH + c;   // right column
    const size_t  rowStride = (size_t)H * CCH;

    float* outp = out + (size_t)bn * NCELL * CCH + (size_t)ix * CCH + c;

    // ---- 7 rows, fully unrolled: compiler pipelines loads across rows ----
    #pragma unroll
    for (int jy = 0; jy < OUT_S; ++jy) {
        const float gy = (float)jy * (1.0f / 6.0f);
        const float cy = (y1 + gy * h) * scale;
        const int   vy = (cy >= 0.0f) & (cy <= (float)(H - 1));
        const float cyc = fminf(fmaxf(cy, 0.0f), (float)(H - 1));
        const int   y0  = (int)floorf(cyc);
        const float yl  = cyc - (float)y0;
        const int   y1i = min(y0 + 1, H - 1);

        const float4 tl = *(const float4*)(col0 + (size_t)y0  * rowStride);
        const float4 tr = *(const float4*)(col1 + (size_t)y0  * rowStride);
        const float4 bl = *(const float4*)(col0 + (size_t)y1i * rowStride);
        const float4 br = *(const float4*)(col1 + (size_t)y1i * rowStride);

        nfloat4 o;
        {
            const float tx = tl.x + (tr.x - tl.x) * xl;
            const float bx = bl.x + (br.x - bl.x) * xl;
            o.x = tx + (bx - tx) * yl;
        }
        {
            const float ty = tl.y + (tr.y - tl.y) * xl;
            const float by = bl.y + (br.y - bl.y) * xl;
            o.y = ty + (by - ty) * yl;
        }
        {
            const float tz = tl.z + (tr.z - tl.z) * xl;
            const float bz = bl.z + (br.z - bl.z) * xl;
            o.z = tz + (bz - tz) * yl;
        }
        {
            const float tw = tl.w + (tr.w - tl.w) * xl;
            const float bw = bl.w + (br.w - bl.w) * xl;
            o.w = tw + (bw - tw) * yl;
        }
        if (!(vx & vy)) { o.x = 0.0f; o.y = 0.0f; o.z = 0.0f; o.w = 0.0f; }

        // write-once output: non-temporal to keep it out of L2
        __builtin_nontemporal_store(
            o, (nfloat4*)(outp + (size_t)jy * OUT_S * CCH));
    }
}

extern "C" void kernel_launch(void* const* d_in, const int* in_sizes, int n_in,
                              void* d_out, int out_size, void* d_ws, size_t ws_size,
                              hipStream_t stream) {
    const float* fm2  = (const float*)d_in[0];
    const float* fm3  = (const float*)d_in[1];
    const float* fm4  = (const float*)d_in[2];
    const float* fm5  = (const float*)d_in[3];
    const float* rois = (const float*)d_in[4];
    float* out = (float*)d_out;

    dim3 grid(B_SZ * N_ROI);        // 1024 blocks, one per ROI
    dim3 block(64 * OUT_S);         // 448 threads = 7 waves = 7 columns
    hipLaunchKernelGGL(roialign_kernel, grid, block, 0, stream,
                       fm2, fm3, fm4, fm5, rois, out);
}

// Round 2
// 221.336 us; speedup vs baseline: 1.0127x; 1.0127x over previous
//
#include <hip/hip_runtime.h>

// ROIAlign (FPN multi-level, crop_and_resize style) for MI355X.
// Shapes (fixed): B=2, N=512, C=256, OUT=7, IMG=1024,
// strides {4,8,16,32} -> fm H=W {256,128,64,32}.
//
// R7 structure: block = 448 threads = 7 waves = HALF a ROI (rows 0-3 or 4-6).
// Wave ix owns output column ix. Fixes both R6 failure modes:
//  - explicit 2-deep register rotation (prefetch row j+1 while lerping row j)
//    -> bounded live set (~64 VGPR, fits the 72-reg cap of (448,7)) and
//       4 loads always in flight per wave, no spill, no serialized rows
//  - 2048 blocks = 2x oversubscription + half-ROI granularity -> load
//    balance across heterogeneous ROI cost (fm2 ROIs are L3-latency,
//    fm5 ROIs are L2-hot); R6's exact-residency had no backfill slack
//  - XCD swizzle kept from R5: blockIdx = 8*(rhi*2+half) + (roi&7), so both
//    halves of a ROI land on the same XCD slot -> one L2 fill per ROI
//  - per-ROI setup (log2/sqrt/level dispatch) computed once per 3-4 rows
//  - NO __syncthreads in the row loop (it would emit vmcnt(0) and drain
//    the prefetch)

#define B_SZ   2
#define N_ROI  512
#define CCH    256
#define OUT_S  7
#define NCELL  (OUT_S * OUT_S)

typedef float nfloat4 __attribute__((ext_vector_type(4)));

struct RowRegs { float4 tl, tr, bl, br; float yl; int vy; };

__device__ __forceinline__ void fetch_row(int jy,
                                          const float* col0, const float* col1,
                                          size_t rowStride,
                                          float y1, float h, float scale, int H,
                                          RowRegs& r)
{
    const float Hm1f = (float)(H - 1);
    const float cy   = (y1 + (float)jy * (1.0f / 6.0f) * h) * scale;
    r.vy = (cy >= 0.0f) & (cy <= Hm1f);
    const float cyc  = fminf(fmaxf(cy, 0.0f), Hm1f);
    const int   y0   = (int)floorf(cyc);
    r.yl = cyc - (float)y0;
    const int   y1i  = min(y0 + 1, H - 1);

    r.tl = *(const float4*)(col0 + (size_t)y0  * rowStride);
    r.tr = *(const float4*)(col1 + (size_t)y0  * rowStride);
    r.bl = *(const float4*)(col0 + (size_t)y1i * rowStride);
    r.br = *(const float4*)(col1 + (size_t)y1i * rowStride);
}

__device__ __forceinline__ void lerp_store(int jy, const RowRegs& r,
                                           float xl, int vx, float* outp)
{
    nfloat4 o;
    {
        const float t  = r.tl.x + (r.tr.x - r.tl.x) * xl;
        const float bo = r.bl.x + (r.br.x - r.bl.x) * xl;
        o.x = t + (bo - t) * r.yl;
    }
    {
        const float t  = r.tl.y + (r.tr.y - r.tl.y) * xl;
        const float bo = r.bl.y + (r.br.y - r.bl.y) * xl;
        o.y = t + (bo - t) * r.yl;
    }
    {
        const float t  = r.tl.z + (r.tr.z - r.tl.z) * xl;
        const float bo = r.bl.z + (r.br.z - r.bl.z) * xl;
        o.z = t + (bo - t) * r.yl;
    }
    {
        const float t  = r.tl.w + (r.tr.w - r.tl.w) * xl;
        const float bo = r.bl.w + (r.br.w - r.bl.w) * xl;
        o.w = t + (bo - t) * r.yl;
    }
    if (!(vx & r.vy)) { o.x = 0.0f; o.y = 0.0f; o.z = 0.0f; o.w = 0.0f; }

    // write-once output: non-temporal to keep it out of L2
    __builtin_nontemporal_store(
        o, (nfloat4*)(outp + (size_t)jy * (OUT_S * CCH)));
}

template<int J0, int J1>
__device__ __forceinline__ void do_rows(const float* col0, const float* col1,
                                        size_t rowStride,
                                        float y1, float h, float scale, int H,
                                        float xl, int vx, float* outp)
{
    RowRegs cur, nxt;
    fetch_row(J0, col0, col1, rowStride, y1, h, scale, H, cur);
    #pragma unroll
    for (int jy = J0; jy < J1; ++jy) {
        if (jy + 1 < J1) {
            // prefetch next row's 4 corners while current row lerps
            fetch_row(jy + 1, col0, col1, rowStride, y1, h, scale, H, nxt);
        }
        lerp_store(jy, cur, xl, vx, outp);
        if (jy + 1 < J1) cur = nxt;   // renamed away by full unroll
    }
}

__global__ __launch_bounds__(448, 7)
void roialign_kernel(const float* __restrict__ fm2,
                     const float* __restrict__ fm3,
                     const float* __restrict__ fm4,
                     const float* __restrict__ fm5,
                     const float* __restrict__ rois,
                     float* __restrict__ out)
{
    // decode swizzled block id -> (roi, half); wave id -> column
    const int bidx = blockIdx.x;
    const int g    = bidx & 7;            // XCD slot == roi & 7
    const int q    = bidx >> 3;           // 0 .. 255
    const int half = q & 1;               // rows 0-3 or 4-6
    const int rhi  = q >> 1;              // 0 .. 127  (roi >> 3)
    const int bn   = (rhi << 3) | g;      // ROI id 0..1023
    const int ix   = threadIdx.x >> 6;    // column 0..6 (wave id in block)
    const int b    = bn >> 9;             // batch (N=512)

    // ---- per-ROI setup (wave-uniform, once per half-ROI) ----
    const float4 roi = ((const float4*)rois)[bn];   // x1,y1,x2,y2
    const float x1 = roi.x, y1 = roi.y;
    const float w  = roi.z - roi.x;
    const float h  = roi.w - roi.y;

    float lvf = log2f(sqrtf(w * h) * (1.0f / 224.0f)) + 4.0f;
    int lv = (int)rintf(lvf);                   // RNE, matches jnp.round
    lv = min(max(lv, 2), 5) - 2;                // 0..3

    const float* fm = (lv == 0) ? fm2 : (lv == 1) ? fm3 : (lv == 2) ? fm4 : fm5;
    const int    H      = 256 >> lv;            // H == W
    const float  stride = (float)(4 << lv);
    const float  scale  = (float)(H - 1) / (stride * (float)H);

    // ---- x-side params: invariant for this column wave ----
    const float gx = (float)ix * (1.0f / 6.0f);
    const float cx = (x1 + gx * w) * scale;     // ref: ((x1+g*w)/stride/W)*(W-1)
    const int   vx = (cx >= 0.0f) & (cx <= (float)(H - 1));
    const float cxc = fminf(fmaxf(cx, 0.0f), (float)(H - 1));
    const int   x0  = (int)floorf(cxc);
    const float xl  = cxc - (float)x0;
    const int   x1i = min(x0 + 1, H - 1);

    const int c = (threadIdx.x & 63) * 4;       // 4 channels per lane

    const float*  base = fm + (size_t)b * (size_t)H * (size_t)H * CCH;
    const float*  col0 = base + (size_t)x0  * CCH + c;   // left  column
    const float*  col1 = base + (size_t)x1i * CCH + c;   // right column
    const size_t  rowStride = (size_t)H * CCH;

    float* outp = out + (size_t)bn * NCELL * CCH + (size_t)ix * CCH + c;

    if (half == 0)
        do_rows<0, 4>(col0, col1, rowStride, y1, h, scale, H, xl, vx, outp);
    else
        do_rows<4, 7>(col0, col1, rowStride, y1, h, scale, H, xl, vx, outp);
}

extern "C" void kernel_launch(void* const* d_in, const int* in_sizes, int n_in,
                              void* d_out, int out_size, void* d_ws, size_t ws_size,
                              hipStream_t stream) {
    const float* fm2  = (const float*)d_in[0];
    const float* fm3  = (const float*)d_in[1];
    const float* fm4  = (const float*)d_in[2];
    const float* fm5  = (const float*)d_in[3];
    const float* rois = (const float*)d_in[4];
    float* out = (float*)d_out;

    dim3 grid(8 * (N_ROI * B_SZ / 8) * 2);   // 2048 blocks (XCD-swizzled halves)
    dim3 block(64 * OUT_S);                  // 448 threads = 7 waves = 7 columns
    hipLaunchKernelGGL(roialign_kernel, grid, block, 0, stream,
                       fm2, fm3, fm4, fm5, rois, out);
}

// Round 3
// 217.189 us; speedup vs baseline: 1.0321x; 1.0191x over previous
//
#include <hip/hip_runtime.h>

// ROIAlign (FPN multi-level, crop_and_resize style) for MI355X.
// Shapes (fixed): B=2, N=512, C=256, OUT=7, IMG=1024,
// strides {4,8,16,32} -> fm H=W {256,128,64,32}.
//
// R8 structure: block = 128 threads = 2 waves = 2 consecutive cells
// (row-major cell order) of one ROI. Rationale vs R5 (448-thr, best so far):
//  - 16 workgroups/CU x 2 waves = 32 waves/CU resident (HW max), vs R5's
//    4 x 7 = 28. Kernel is latency-bound (short-lived waves: gather ->
//    lerp -> store -> exit); TLP is the only latency hider -> +14% slots.
//    (64-thread blocks would hit the 16-wg/CU limit = 16 waves: worse.)
//  - 25 blocks per ROI -> even finer load-balance granularity than R5's 7
//    (R6/R7 showed coarse blocks regress; this goes the other way).
//  - XCD swizzle kept: blockIdx = 8*(rhi*25 + p) + (roi&7), all blocks of
//    a ROI land on the same XCD slot -> ROI pixel set fills ONE L2.
//  - pair = cells 2p, 2p+1: usually same row, adjacent columns -> the two
//    waves share bilinear y-rows (partial L1 reuse kept). Cell 49 (pad)
//    masked off; no barriers anywhere so early-exit is free.

#define B_SZ   2
#define N_ROI  512
#define CCH    256
#define OUT_S  7
#define NCELL  (OUT_S * OUT_S)
#define PAIRS  25                      // ceil(49 / 2)

typedef float nfloat4 __attribute__((ext_vector_type(4)));

__global__ __launch_bounds__(128)
void roialign_kernel(const float* __restrict__ fm2,
                     const float* __restrict__ fm3,
                     const float* __restrict__ fm4,
                     const float* __restrict__ fm5,
                     const float* __restrict__ rois,
                     float* __restrict__ out)
{
    // decode swizzled block id -> (roi, cell pair); wave id -> which cell
    const int bidx = blockIdx.x;
    const int g    = bidx & 7;            // XCD slot == roi & 7
    const int q    = bidx >> 3;           // 0 .. 3199
    const int rhi  = q / PAIRS;           // 0 .. 127  (roi >> 3)
    const int p    = q - rhi * PAIRS;     // pair 0..24
    const int bn   = (rhi << 3) | g;      // ROI id 0..1023
    const int w_id = threadIdx.x >> 6;    // wave 0/1
    const int cell = 2 * p + w_id;        // 0..49
    if (cell >= NCELL) return;            // pad wave (no barriers -> safe)
    const int jy   = cell / OUT_S;        // row 0..6
    const int ix   = cell - jy * OUT_S;   // col 0..6
    const int b    = bn >> 9;             // batch (N=512)

    // ---- per-ROI setup (wave-uniform) ----
    const float4 roi = ((const float4*)rois)[bn];   // x1,y1,x2,y2
    const float x1 = roi.x, y1 = roi.y;
    const float w  = roi.z - roi.x;
    const float h  = roi.w - roi.y;

    float lvf = log2f(sqrtf(w * h) * (1.0f / 224.0f)) + 4.0f;
    int lv = (int)rintf(lvf);                   // RNE, matches jnp.round
    lv = min(max(lv, 2), 5) - 2;                // 0..3

    const float* fm = (lv == 0) ? fm2 : (lv == 1) ? fm3 : (lv == 2) ? fm4 : fm5;
    const int    H      = 256 >> lv;            // H == W
    const float  stride = (float)(4 << lv);
    const float  scale  = (float)(H - 1) / (stride * (float)H);

    // ---- sample coordinate for this (row, col) cell ----
    const float gy = (float)jy * (1.0f / 6.0f);
    const float gx = (float)ix * (1.0f / 6.0f);
    const float cy = (y1 + gy * h) * scale;     // ref: ((y1+g*h)/stride/H)*(H-1)
    const float cx = (x1 + gx * w) * scale;

    const int vld = (cy >= 0.0f) & (cy <= (float)(H - 1)) &
                    (cx >= 0.0f) & (cx <= (float)(H - 1));

    const float cyc = fminf(fmaxf(cy, 0.0f), (float)(H - 1));
    const float cxc = fminf(fmaxf(cx, 0.0f), (float)(H - 1));
    const int   y0  = (int)floorf(cyc);
    const int   x0  = (int)floorf(cxc);
    const float yl  = cyc - (float)y0;
    const float xl  = cxc - (float)x0;
    const int   y1i = min(y0 + 1, H - 1);
    const int   x1i = min(x0 + 1, H - 1);

    // ---- gather + bilinear: lane handles 4 channels (float4) ----
    const int c = (threadIdx.x & 63) * 4;

    const float* base = fm + (size_t)b * (size_t)H * (size_t)H * CCH;
    const float* rowT = base + (size_t)y0  * H * CCH;
    const float* rowB = base + (size_t)y1i * H * CCH;

    const float4 tl = *(const float4*)(rowT + x0  * CCH + c);
    const float4 tr = *(const float4*)(rowT + x1i * CCH + c);
    const float4 bl = *(const float4*)(rowB + x0  * CCH + c);
    const float4 br = *(const float4*)(rowB + x1i * CCH + c);

    nfloat4 o;
    {
        const float tx = tl.x + (tr.x - tl.x) * xl;
        const float bx = bl.x + (br.x - bl.x) * xl;
        o.x = tx + (bx - tx) * yl;
    }
    {
        const float ty = tl.y + (tr.y - tl.y) * xl;
        const float by = bl.y + (br.y - bl.y) * xl;
        o.y = ty + (by - ty) * yl;
    }
    {
        const float tz = tl.z + (tr.z - tl.z) * xl;
        const float bz = bl.z + (br.z - bl.z) * xl;
        o.z = tz + (bz - tz) * yl;
    }
    {
        const float tw = tl.w + (tr.w - tl.w) * xl;
        const float bw = bl.w + (br.w - bl.w) * xl;
        o.w = tw + (bw - tw) * yl;
    }
    if (!vld) { o.x = 0.0f; o.y = 0.0f; o.z = 0.0f; o.w = 0.0f; }

    // write-once output: non-temporal to keep it out of L2
    nfloat4* dst = (nfloat4*)(out + (size_t)bn * NCELL * CCH
                                  + (size_t)cell * CCH + c);
    __builtin_nontemporal_store(o, dst);
}

extern "C" void kernel_launch(void* const* d_in, const int* in_sizes, int n_in,
                              void* d_out, int out_size, void* d_ws, size_t ws_size,
                              hipStream_t stream) {
    const float* fm2  = (const float*)d_in[0];
    const float* fm3  = (const float*)d_in[1];
    const float* fm4  = (const float*)d_in[2];
    const float* fm5  = (const float*)d_in[3];
    const float* rois = (const float*)d_in[4];
    float* out = (float*)d_out;

    dim3 grid(8 * (N_ROI * B_SZ / 8) * PAIRS);   // 25600 blocks (XCD-swizzled)
    dim3 block(128);                             // 2 waves = 2 cells
    hipLaunchKernelGGL(roialign_kernel, grid, block, 0, stream,
                       fm2, fm3, fm4, fm5, rois, out);
}